// Round 2
// baseline (364.098 us; speedup 1.0000x reference)
//
#include <hip/hip_runtime.h>
#include <hip/hip_bf16.h>

// Problem constants (fixed by reference setup_inputs)
constexpr int HEADS = 8;
constexpr int B = 4;
constexpr int BH = B * HEADS;   // 32
constexpr int T = 16384;
constexpr int DH = 64;
constexpr int NB = 128;          // MAX_BUCKETS
constexpr int DIM = 128;         // 2*DH
constexpr float EPS = 1e-6f;
constexpr float INV_TEMP = 1.0f / 0.7f;

constexpr int CHUNK = 1024;      // timesteps per segsum block

// ---------------------------------------------------------------------------
// K1: segment sum of q and k into x[bh][bucket][0:64]=sum q, [64:128]=sum k.
// segment_ids are sorted along T, so run-length accumulate in registers,
// flush to LDS bucket table on change, then one global atomicAdd pass over
// the block's touched bucket range. x must be pre-zeroed.
// ---------------------------------------------------------------------------
__global__ __launch_bounds__(256) void k_segsum(
    const float* __restrict__ q, const float* __restrict__ k,
    const int* __restrict__ seg, float* __restrict__ x) {
  const int bh = blockIdx.y;
  const int b = bh >> 3;                 // bh / HEADS
  const int t0 = blockIdx.x * CHUNK;
  const int tid = threadIdx.x;

  __shared__ float sums[NB][2 * DH];     // 64 KB
  __shared__ int ids[CHUNK];             // 4 KB

  for (int i = tid; i < CHUNK; i += 256) ids[i] = seg[(size_t)b * T + t0 + i];
  __syncthreads();

  const int bmin = ids[0];
  const int bmax = ids[CHUNK - 1];
  const int nzero = (bmax - bmin + 1) * 128;
  float* sflat = &sums[bmin][0];
  for (int i = tid; i < nzero; i += 256) sflat[i] = 0.f;
  __syncthreads();

  // lane layout: slot 0..15 -> q float4 #slot, slot 16..31 -> k float4 #(slot-16)
  const int slot = tid & 31;
  const int grp = tid >> 5;              // 0..7, strides over t
  const bool isq = slot < 16;
  const int f4 = slot & 15;
  const float4* src =
      (const float4*)((isq ? q : k) + (size_t)bh * T * DH) + (size_t)t0 * 16 + f4;
  const int loff = (isq ? 0 : DH) + f4 * 4;

  float4 acc = make_float4(0.f, 0.f, 0.f, 0.f);
  int cur = -1;
  for (int t = grp; t < CHUNK; t += 8) {
    const int bk = ids[t];
    const float4 v = src[(size_t)t * 16];
    if (bk != cur) {
      if (cur >= 0) {
        atomicAdd(&sums[cur][loff + 0], acc.x);
        atomicAdd(&sums[cur][loff + 1], acc.y);
        atomicAdd(&sums[cur][loff + 2], acc.z);
        atomicAdd(&sums[cur][loff + 3], acc.w);
      }
      acc = v;
      cur = bk;
    } else {
      acc.x += v.x; acc.y += v.y; acc.z += v.z; acc.w += v.w;
    }
  }
  if (cur >= 0) {
    atomicAdd(&sums[cur][loff + 0], acc.x);
    atomicAdd(&sums[cur][loff + 1], acc.y);
    atomicAdd(&sums[cur][loff + 2], acc.z);
    atomicAdd(&sums[cur][loff + 3], acc.w);
  }
  __syncthreads();

  float* xp = x + (size_t)bh * NB * 128 + (size_t)bmin * 128;
  for (int i = tid; i < nzero; i += 256) {
    const float v = sflat[i];
    if (v != 0.f) atomicAdd(&xp[i], v);
  }
}

// ---------------------------------------------------------------------------
// K2a: R = relu(x @ W), r0 = (log(R+eps) + gumbel)/temp. One block per
// (bh, 16-row chunk). x rows staged in LDS; W streamed from L2.
// ---------------------------------------------------------------------------
__global__ __launch_bounds__(256) void k_matmul(
    const float* __restrict__ x, const float* __restrict__ linear,
    const float* __restrict__ gumbel, float* __restrict__ r0) {
  const int bh = blockIdx.y;
  const int n0 = blockIdx.x * 16;
  const int h = bh & 7;                  // bh % HEADS
  const int tid = threadIdx.x;

  __shared__ float xs[16][DIM];          // 8 KB

  const float4* xp = (const float4*)(x + ((size_t)bh * NB + n0) * DIM);
  for (int i = tid; i < 16 * 32; i += 256) {
    const float4 v = xp[i];
    const int n = i >> 5, d4 = i & 31;
    xs[n][d4 * 4 + 0] = v.x;
    xs[n][d4 * 4 + 1] = v.y;
    xs[n][d4 * 4 + 2] = v.z;
    xs[n][d4 * 4 + 3] = v.w;
  }
  __syncthreads();

  const int mt = tid & 31;               // output col float4
  const int rp = tid >> 5;               // 0..7 row pair
  const int ra = rp * 2;

  float4 a0 = make_float4(0.f, 0.f, 0.f, 0.f);
  float4 a1 = make_float4(0.f, 0.f, 0.f, 0.f);
  const float4* Wp = (const float4*)(linear + (size_t)h * DIM * NB);
  for (int d4 = 0; d4 < 32; d4++) {
    const float4 xv0 = *(const float4*)&xs[ra][d4 * 4];
    const float4 xv1 = *(const float4*)&xs[ra + 1][d4 * 4];
    const float4 w0 = Wp[(d4 * 4 + 0) * 32 + mt];
    const float4 w1 = Wp[(d4 * 4 + 1) * 32 + mt];
    const float4 w2 = Wp[(d4 * 4 + 2) * 32 + mt];
    const float4 w3 = Wp[(d4 * 4 + 3) * 32 + mt];
    a0.x += xv0.x * w0.x + xv0.y * w1.x + xv0.z * w2.x + xv0.w * w3.x;
    a0.y += xv0.x * w0.y + xv0.y * w1.y + xv0.z * w2.y + xv0.w * w3.y;
    a0.z += xv0.x * w0.z + xv0.y * w1.z + xv0.z * w2.z + xv0.w * w3.z;
    a0.w += xv0.x * w0.w + xv0.y * w1.w + xv0.z * w2.w + xv0.w * w3.w;
    a1.x += xv1.x * w0.x + xv1.y * w1.x + xv1.z * w2.x + xv1.w * w3.x;
    a1.y += xv1.x * w0.y + xv1.y * w1.y + xv1.z * w2.y + xv1.w * w3.y;
    a1.z += xv1.x * w0.z + xv1.y * w1.z + xv1.z * w2.z + xv1.w * w3.z;
    a1.w += xv1.x * w0.w + xv1.y * w1.w + xv1.z * w2.w + xv1.w * w3.w;
  }

  const float4* gp = (const float4*)(gumbel + ((size_t)bh * NB + n0) * NB);
  float4* op = (float4*)(r0 + ((size_t)bh * NB + n0) * NB);

  auto xform = [](float a, float u) {
    const float R = fmaxf(a, 0.f);
    const float g = -logf(-logf(u + EPS) + EPS);
    return (logf(R + EPS) + g) * INV_TEMP;
  };
  {
    const float4 u = gp[(size_t)ra * 32 + mt];
    float4 o;
    o.x = xform(a0.x, u.x); o.y = xform(a0.y, u.y);
    o.z = xform(a0.z, u.z); o.w = xform(a0.w, u.w);
    op[(size_t)ra * 32 + mt] = o;
  }
  {
    const float4 u = gp[(size_t)(ra + 1) * 32 + mt];
    float4 o;
    o.x = xform(a1.x, u.x); o.y = xform(a1.y, u.y);
    o.z = xform(a1.z, u.z); o.w = xform(a1.w, u.w);
    op[(size_t)(ra + 1) * 32 + mt] = o;
  }
}

// ---------------------------------------------------------------------------
// K2b: 8 Sinkhorn iterations + exp, one block per bh, r in LDS [128][129].
// Reads r0 (== d_out) fully into LDS before writing final result back.
// 4 lanes per row/col, j staggered by qp*8 -> 2-way LDS access (free).
// ---------------------------------------------------------------------------
__global__ __launch_bounds__(512) void k_sinkhorn(
    const float* __restrict__ r0, float* __restrict__ out) {
  const int bh = blockIdx.x;
  const int tid = threadIdx.x;

  __shared__ float r[NB][NB + 1];        // 66 KB
  __shared__ float lse_r[NB];
  __shared__ float lse_c[NB];

  const float4* rp = (const float4*)(r0 + (size_t)bh * NB * NB);
  for (int i = tid; i < NB * 32; i += 512) {
    const float4 v = rp[i];
    const int n = i >> 5, m4 = i & 31;
    r[n][m4 * 4 + 0] = v.x;
    r[n][m4 * 4 + 1] = v.y;
    r[n][m4 * 4 + 2] = v.z;
    r[n][m4 * 4 + 3] = v.w;
  }
  __syncthreads();

  const int row = tid >> 2;              // 0..127 (row for pass1, col for pass2)
  const int qp = tid & 3;                // quarter within row/col

  for (int it = 0; it < 8; it++) {
    // ---- row logsumexp (axis=2) ----
    float mx = -1e30f;
#pragma unroll
    for (int j = 0; j < 32; j++) {
      const int m = qp * 32 + ((j + qp * 8) & 31);
      mx = fmaxf(mx, r[row][m]);
    }
    mx = fmaxf(mx, __shfl_xor(mx, 1));
    mx = fmaxf(mx, __shfl_xor(mx, 2));
    float s = 0.f;
#pragma unroll
    for (int j = 0; j < 32; j++) {
      const int m = qp * 32 + ((j + qp * 8) & 31);
      s += expf(r[row][m] - mx);
    }
    s += __shfl_xor(s, 1);
    s += __shfl_xor(s, 2);
    if (qp == 0) lse_r[row] = mx + logf(s);
    __syncthreads();

    // ---- col logsumexp (axis=1) over (r - lse_r) ----
    const int col = row;
    float cmx = -1e30f;
#pragma unroll
    for (int j = 0; j < 32; j++) {
      const int n = qp * 32 + ((j + qp * 8) & 31);
      cmx = fmaxf(cmx, r[n][col] - lse_r[n]);
    }
    cmx = fmaxf(cmx, __shfl_xor(cmx, 1));
    cmx = fmaxf(cmx, __shfl_xor(cmx, 2));
    float cs = 0.f;
#pragma unroll
    for (int j = 0; j < 32; j++) {
      const int n = qp * 32 + ((j + qp * 8) & 31);
      cs += expf(r[n][col] - lse_r[n] - cmx);
    }
    cs += __shfl_xor(cs, 1);
    cs += __shfl_xor(cs, 2);
    if (qp == 0) lse_c[col] = cmx + logf(cs);
    __syncthreads();

    // ---- combined update: r -= lse_r[n] + lse_c[m] ----
    const float lr = lse_r[row];
#pragma unroll
    for (int j = 0; j < 32; j++) {
      const int m = qp * 32 + ((j + qp * 8) & 31);
      r[row][m] = r[row][m] - lr - lse_c[m];
    }
    __syncthreads();
  }

  float* op = out + (size_t)bh * NB * NB;
  for (int i = tid; i < NB * NB; i += 512) {
    const int n = i >> 7, m = i & 127;
    op[i] = expf(r[n][m]);
  }
}

// ---------------------------------------------------------------------------
extern "C" void kernel_launch(void* const* d_in, const int* in_sizes, int n_in,
                              void* d_out, int out_size, void* d_ws, size_t ws_size,
                              hipStream_t stream) {
  const float* q = (const float*)d_in[0];
  const float* k = (const float*)d_in[1];
  const float* linear = (const float*)d_in[2];   // (1, 8, 128, 128)
  const int* seg = (const int*)d_in[3];          // (4, 16384)
  const float* gum = (const float*)d_in[4];      // (32, 128, 128)
  float* out = (float*)d_out;                    // (32, 128, 128) f32

  float* x = (float*)d_ws;                       // (32, 128, 128) f32 scratch
  float* r0 = out;                               // stage r0 in d_out (2 MB)

  hipMemsetAsync(x, 0, (size_t)BH * NB * DIM * sizeof(float), stream);

  dim3 g1(T / CHUNK, BH);
  k_segsum<<<g1, 256, 0, stream>>>(q, k, seg, x);

  dim3 g2(8, BH);
  k_matmul<<<g2, 256, 0, stream>>>(x, linear, gum, r0);

  k_sinkhorn<<<BH, 512, 0, stream>>>(r0, out);
}

// Round 4
// 331.657 us; speedup vs baseline: 1.0978x; 1.0978x over previous
//
#include <hip/hip_runtime.h>
#include <hip/hip_bf16.h>

// Problem constants (fixed by reference setup_inputs)
constexpr int HEADS = 8;
constexpr int B = 4;
constexpr int BH = B * HEADS;   // 32
constexpr int T = 16384;
constexpr int DH = 64;
constexpr int NB = 128;          // MAX_BUCKETS
constexpr int DIM = 128;         // 2*DH
constexpr float EPS = 1e-6f;
constexpr float INV_TEMP = 1.0f / 0.7f;

constexpr int CHUNK = 1024;      // timesteps per segsum block
constexpr int TPG = 128;         // contiguous timesteps per thread-group

// ---------------------------------------------------------------------------
// K1: segment sum of q and k into x[bh][bucket][0:64]=sum q, [64:128]=sum k.
// segment_ids are sorted along T: run-length accumulate a float4 in registers,
// flush straight to global atomicAdd on bucket change (x is L2-resident, 2MB).
// No LDS bucket table -> 4KB LDS, high occupancy; 8-deep load batching.
// ---------------------------------------------------------------------------
__global__ __launch_bounds__(256) void k_segsum(
    const float* __restrict__ q, const float* __restrict__ k,
    const int* __restrict__ seg, float* __restrict__ x) {
  const int bh = blockIdx.y;
  const int b = bh >> 3;                 // bh / HEADS
  const int t0 = blockIdx.x * CHUNK;
  const int tid = threadIdx.x;

  __shared__ int ids[CHUNK];             // 4 KB
  for (int i = tid; i < CHUNK; i += 256) ids[i] = seg[(size_t)b * T + t0 + i];
  __syncthreads();

  // lane layout: slot 0..15 -> q float4 #slot, slot 16..31 -> k float4 #(slot-16)
  // grp 0..7 -> contiguous 128-timestep range (few bucket transitions per range)
  const int slot = tid & 31;
  const int grp = tid >> 5;
  const bool isq = slot < 16;
  const int f4 = slot & 15;
  const int base = grp * TPG;
  const float4* src = (const float4*)((isq ? q : k) + (size_t)bh * T * DH) +
                      (size_t)(t0 + base) * 16 + f4;
  float* xb = x + (size_t)bh * NB * 128 + (isq ? 0 : DH) + f4 * 4;

  float4 acc = make_float4(0.f, 0.f, 0.f, 0.f);
  int cur = ids[base];

  for (int j = 0; j < TPG; j += 8) {
    float4 v0 = src[(size_t)(j + 0) * 16];
    float4 v1 = src[(size_t)(j + 1) * 16];
    float4 v2 = src[(size_t)(j + 2) * 16];
    float4 v3 = src[(size_t)(j + 3) * 16];
    float4 v4 = src[(size_t)(j + 4) * 16];
    float4 v5 = src[(size_t)(j + 5) * 16];
    float4 v6 = src[(size_t)(j + 6) * 16];
    float4 v7 = src[(size_t)(j + 7) * 16];
    int i0 = ids[base + j + 0], i1 = ids[base + j + 1];
    int i2 = ids[base + j + 2], i3 = ids[base + j + 3];
    int i4 = ids[base + j + 4], i5 = ids[base + j + 5];
    int i6 = ids[base + j + 6], i7 = ids[base + j + 7];

    auto step = [&](int bk, const float4& v) {
      if (bk != cur) {
        float* p = xb + (size_t)cur * 128;
        atomicAdd(p + 0, acc.x);
        atomicAdd(p + 1, acc.y);
        atomicAdd(p + 2, acc.z);
        atomicAdd(p + 3, acc.w);
        acc = v;
        cur = bk;
      } else {
        acc.x += v.x; acc.y += v.y; acc.z += v.z; acc.w += v.w;
      }
    };
    step(i0, v0); step(i1, v1); step(i2, v2); step(i3, v3);
    step(i4, v4); step(i5, v5); step(i6, v6); step(i7, v7);
  }
  {
    float* p = xb + (size_t)cur * 128;
    atomicAdd(p + 0, acc.x);
    atomicAdd(p + 1, acc.y);
    atomicAdd(p + 2, acc.z);
    atomicAdd(p + 3, acc.w);
  }
}

// ---------------------------------------------------------------------------
// K2a: R = relu(x @ W), r0 = (log(R+eps) + gumbel)/temp. One block per
// (bh, 16-row chunk). x rows staged in LDS; W streamed from L1/L2.
// ---------------------------------------------------------------------------
__global__ __launch_bounds__(256) void k_matmul(
    const float* __restrict__ x, const float* __restrict__ linear,
    const float* __restrict__ gumbel, float* __restrict__ r0) {
  const int bh = blockIdx.y;
  const int n0 = blockIdx.x * 16;
  const int h = bh & 7;                  // bh % HEADS
  const int tid = threadIdx.x;

  __shared__ float xs[16][DIM];          // 8 KB

  const float4* xp = (const float4*)(x + ((size_t)bh * NB + n0) * DIM);
  for (int i = tid; i < 16 * 32; i += 256) {
    const float4 v = xp[i];
    const int n = i >> 5, d4 = i & 31;
    xs[n][d4 * 4 + 0] = v.x;
    xs[n][d4 * 4 + 1] = v.y;
    xs[n][d4 * 4 + 2] = v.z;
    xs[n][d4 * 4 + 3] = v.w;
  }
  __syncthreads();

  const int mt = tid & 31;               // output col float4
  const int rp = tid >> 5;               // 0..7 row pair
  const int ra = rp * 2;

  float4 a0 = make_float4(0.f, 0.f, 0.f, 0.f);
  float4 a1 = make_float4(0.f, 0.f, 0.f, 0.f);
  const float4* Wp = (const float4*)(linear + (size_t)h * DIM * NB);
  for (int d4 = 0; d4 < 32; d4++) {
    const float4 xv0 = *(const float4*)&xs[ra][d4 * 4];
    const float4 xv1 = *(const float4*)&xs[ra + 1][d4 * 4];
    const float4 w0 = Wp[(d4 * 4 + 0) * 32 + mt];
    const float4 w1 = Wp[(d4 * 4 + 1) * 32 + mt];
    const float4 w2 = Wp[(d4 * 4 + 2) * 32 + mt];
    const float4 w3 = Wp[(d4 * 4 + 3) * 32 + mt];
    a0.x += xv0.x * w0.x + xv0.y * w1.x + xv0.z * w2.x + xv0.w * w3.x;
    a0.y += xv0.x * w0.y + xv0.y * w1.y + xv0.z * w2.y + xv0.w * w3.y;
    a0.z += xv0.x * w0.z + xv0.y * w1.z + xv0.z * w2.z + xv0.w * w3.z;
    a0.w += xv0.x * w0.w + xv0.y * w1.w + xv0.z * w2.w + xv0.w * w3.w;
    a1.x += xv1.x * w0.x + xv1.y * w1.x + xv1.z * w2.x + xv1.w * w3.x;
    a1.y += xv1.x * w0.y + xv1.y * w1.y + xv1.z * w2.y + xv1.w * w3.y;
    a1.z += xv1.x * w0.z + xv1.y * w1.z + xv1.z * w2.z + xv1.w * w3.z;
    a1.w += xv1.x * w0.w + xv1.y * w1.w + xv1.z * w2.w + xv1.w * w3.w;
  }

  const float4* gp = (const float4*)(gumbel + ((size_t)bh * NB + n0) * NB);
  float4* op = (float4*)(r0 + ((size_t)bh * NB + n0) * NB);

  auto xform = [](float a, float u) {
    const float R = fmaxf(a, 0.f);
    const float g = -__logf(-__logf(u + EPS) + EPS);
    return (__logf(R + EPS) + g) * INV_TEMP;
  };
  {
    const float4 u = gp[(size_t)ra * 32 + mt];
    float4 o;
    o.x = xform(a0.x, u.x); o.y = xform(a0.y, u.y);
    o.z = xform(a0.z, u.z); o.w = xform(a0.w, u.w);
    op[(size_t)ra * 32 + mt] = o;
  }
  {
    const float4 u = gp[(size_t)(ra + 1) * 32 + mt];
    float4 o;
    o.x = xform(a1.x, u.x); o.y = xform(a1.y, u.y);
    o.z = xform(a1.z, u.z); o.w = xform(a1.w, u.w);
    op[(size_t)(ra + 1) * 32 + mt] = o;
  }
}

// ---------------------------------------------------------------------------
// K2b: 8 Sinkhorn iterations + exp. One block (512 threads) per bh.
// Row state in REGISTERS: thread (row=tid>>2, qp=tid&3) owns r[row][qp*32+j].
// Per iter: row-LSE pure regs+shfl -> write to LDS image -> staggered
// conflict-free column read -> col-LSE -> broadcast lse_c subtract.
// 2 barriers/iter, 97 LDS ops/thread/iter.
// ---------------------------------------------------------------------------
__global__ __launch_bounds__(512) void k_sinkhorn(
    const float* __restrict__ r0, float* __restrict__ out) {
  const int bh = blockIdx.x;
  const int tid = threadIdx.x;

  __shared__ float img[NB * (NB + 1)];   // stride 129, 66 KB
  __shared__ float lse_c[NB];

  const int row = tid >> 2;              // 0..127 (col index in col pass)
  const int qp = tid & 3;                // quarter

  float rr[32];
  {
    const float4* rp =
        (const float4*)(r0 + (size_t)bh * NB * NB + row * NB + qp * 32);
#pragma unroll
    for (int u = 0; u < 8; u++) {
      const float4 v = rp[u];
      rr[4 * u + 0] = v.x; rr[4 * u + 1] = v.y;
      rr[4 * u + 2] = v.z; rr[4 * u + 3] = v.w;
    }
  }

  for (int it = 0; it < 8; it++) {
    // ---- row logsumexp (pure registers + 2 shfl) ----
    float m = rr[0];
#pragma unroll
    for (int j = 1; j < 32; j++) m = fmaxf(m, rr[j]);
    m = fmaxf(m, __shfl_xor(m, 1));
    m = fmaxf(m, __shfl_xor(m, 2));
    float s = 0.f;
#pragma unroll
    for (int j = 0; j < 32; j++) s += __expf(rr[j] - m);
    s += __shfl_xor(s, 1);
    s += __shfl_xor(s, 2);
    const float lse = m + __logf(s);
#pragma unroll
    for (int j = 0; j < 32; j++) rr[j] -= lse;

    // ---- publish row-normalized values ----
#pragma unroll
    for (int j = 0; j < 32; j++) img[row * (NB + 1) + qp * 32 + j] = rr[j];
    __syncthreads();

    // ---- column logsumexp: col c = row; rows n = qp*32 + stagger(j) ----
    float tmp[32];
#pragma unroll
    for (int j = 0; j < 32; j++) {
      const int n = qp * 32 + ((j + qp * 8) & 31);
      tmp[j] = img[n * (NB + 1) + row];
    }
    float cm = tmp[0];
#pragma unroll
    for (int j = 1; j < 32; j++) cm = fmaxf(cm, tmp[j]);
    cm = fmaxf(cm, __shfl_xor(cm, 1));
    cm = fmaxf(cm, __shfl_xor(cm, 2));
    float cs = 0.f;
#pragma unroll
    for (int j = 0; j < 32; j++) cs += __expf(tmp[j] - cm);
    cs += __shfl_xor(cs, 1);
    cs += __shfl_xor(cs, 2);
    if (qp == 0) lse_c[row] = cm + __logf(cs);
    __syncthreads();

    // ---- subtract column lse (broadcast reads) ----
#pragma unroll
    for (int j = 0; j < 32; j++) rr[j] -= lse_c[qp * 32 + j];
  }

  // ---- output exp(r) ----
  {
    float4* op = (float4*)(out + (size_t)bh * NB * NB + row * NB + qp * 32);
#pragma unroll
    for (int u = 0; u < 8; u++) {
      float4 v;
      v.x = __expf(rr[4 * u + 0]);
      v.y = __expf(rr[4 * u + 1]);
      v.z = __expf(rr[4 * u + 2]);
      v.w = __expf(rr[4 * u + 3]);
      op[u] = v;
    }
  }
}

// ---------------------------------------------------------------------------
extern "C" void kernel_launch(void* const* d_in, const int* in_sizes, int n_in,
                              void* d_out, int out_size, void* d_ws, size_t ws_size,
                              hipStream_t stream) {
  const float* q = (const float*)d_in[0];
  const float* k = (const float*)d_in[1];
  const float* linear = (const float*)d_in[2];   // (1, 8, 128, 128)
  const int* seg = (const int*)d_in[3];          // (4, 16384)
  const float* gum = (const float*)d_in[4];      // (32, 128, 128)
  float* out = (float*)d_out;                    // (32, 128, 128) f32

  float* x = (float*)d_ws;                       // (32, 128, 128) f32 scratch
  float* r0 = out;                               // stage r0 in d_out (2 MB)

  hipMemsetAsync(x, 0, (size_t)BH * NB * DIM * sizeof(float), stream);

  dim3 g1(T / CHUNK, BH);
  k_segsum<<<g1, 256, 0, stream>>>(q, k, seg, x);

  dim3 g2(8, BH);
  k_matmul<<<g2, 256, 0, stream>>>(x, linear, gum, r0);

  k_sinkhorn<<<BH, 512, 0, stream>>>(r0, out);
}